// Round 16
// baseline (133.219 us; speedup 1.0000x reference)
//
#include <hip/hip_runtime.h>
#include <hip/hip_bf16.h>

// Problem constants
#define BB 512
#define LL 1024
#define AA 13
#define NBP 5
#define NTOT (BB * LL)
#define EPSV 1e-5f

// ws layout (floats)
#define WS_F     192       // 10: F[nn] = sum over half-l of flw
#define WS_PART  256       // 256 blocks * 40 moment partials
#define WS_CONST 10496     // 64 channels * 16 packed consts (written by k_prep)
#define WS_FLW   16384     // 64KB region: flw bf16 hi plane [0,32K)B, lo plane [32K,64K)B, 16 rows x 1024

typedef __attribute__((ext_vector_type(8))) short bhalf8;   // 8 bf16 in 4 VGPRs (MFMA A/B frag)
typedef __attribute__((ext_vector_type(4))) float floatx4;  // MFMA C/D frag

// ---- truncation hi/lo split, packed 2-at-a-time (r1/r2/r6/r9-proven numerics: absmax 0.0039) ----
__device__ __forceinline__ void trunc_pair(float e0, float e1, unsigned int& hp, unsigned int& lp) {
    unsigned int u0 = __float_as_uint(e0), u1 = __float_as_uint(e1);
    unsigned int h0 = u0 & 0xFFFF0000u, h1 = u1 & 0xFFFF0000u;
    hp = (h0 >> 16) | h1;
    float l0 = e0 - __uint_as_float(h0);
    float l1 = e1 - __uint_as_float(h1);
    lp = (__float_as_uint(l0) >> 16) | (__float_as_uint(l1) & 0xFFFF0000u);
}

// ---- DPP wave64 sum: result valid in lane 63 (VALU pipe, no LDS) ----
template<int CTRL, int RM, bool BC>
__device__ __forceinline__ float dppadd(float v) {
    int t = __builtin_amdgcn_update_dpp(0, __float_as_int(v), CTRL, RM, 0xf, BC);
    return v + __int_as_float(t);
}
__device__ __forceinline__ float wave_sum(float v) {
    v = dppadd<0x111, 0xf, true >(v);   // row_shr:1
    v = dppadd<0x112, 0xf, true >(v);   // row_shr:2
    v = dppadd<0x114, 0xf, true >(v);   // row_shr:4
    v = dppadd<0x118, 0xf, true >(v);   // row_shr:8
    v = dppadd<0x142, 0xa, false>(v);   // row_bcast15
    v = dppadd<0x143, 0xc, false>(v);   // row_bcast31 -> lane63 total
    return v;
}

// ---- e from packed dv slots + per-channel consts ----
__device__ __forceinline__ float e_val(const float4& A, const float4& B2, const float4& R0, float r4w,
                                       const float4& pa, const float4& pb, float svx, float svy) {
    float y = B2.y + A.x*pa.x + A.y*pa.y + A.z*pa.z + A.w*pa.w + B2.x*pb.x;
    float r = B2.z + R0.x*pb.y + R0.y*pb.z + R0.z*pb.w + R0.w*svx + r4w*svy;
    return fmaxf(y, 0.f) * r;
}

// ---------------- Kernel 1: moment partials + flw half-row sums + flw bf16 hi/lo prepack ----------------
// (r9-verbatim, proven: 256 blocks x 256 thr, 8-wide strips)
__global__ __launch_bounds__(256) void k_moments(
    const float* __restrict__ src,
    const float* __restrict__ dw1,
    const float* __restrict__ dw2,
    const float* __restrict__ flw,
    float* __restrict__ ws)
{
    __shared__ float red[4][40];
    __shared__ float fred[4];
    int tid = threadIdx.x;
    int gid = blockIdx.x * 256 + tid;
    int b = gid >> 7, L0 = (gid & 127) << 3;     // 8-wide strip per thread
    const float* sb = src + b * (5 * LL);

    float w1[5][5], w2[5][3];
#pragma unroll
    for (int c = 0; c < 5; c++) {
#pragma unroll
        for (int t = 0; t < 5; t++) w1[c][t] = dw1[c*5+t];
#pragma unroll
        for (int t = 0; t < 3; t++) w2[c][t] = dw2[c*3+t];
    }

    // x[c5][m] covers l = L0-4 .. L0+11
    float x[5][16];
#pragma unroll
    for (int c5 = 0; c5 < 5; c5++) {
        const float* sp = sb + c5 * LL;
        float4 xa = (L0 >= 4)    ? *(const float4*)(sp + L0 - 4) : make_float4(0,0,0,0);
        float4 xb = *(const float4*)(sp + L0);
        float4 xc = *(const float4*)(sp + L0 + 4);
        float4 xd = (L0 <= 1012) ? *(const float4*)(sp + L0 + 8) : make_float4(0,0,0,0);
        x[c5][0]=xa.x; x[c5][1]=xa.y; x[c5][2]=xa.z; x[c5][3]=xa.w;
        x[c5][4]=xb.x; x[c5][5]=xb.y; x[c5][6]=xb.z; x[c5][7]=xb.w;
        x[c5][8]=xc.x; x[c5][9]=xc.y; x[c5][10]=xc.z; x[c5][11]=xc.w;
        x[c5][12]=xd.x; x[c5][13]=xd.y; x[c5][14]=xd.z; x[c5][15]=xd.w;
    }

    float acc[40];
#pragma unroll
    for (int k = 0; k < 40; k++) acc[k] = 0.f;

#pragma unroll
    for (int k = 0; k < 8; k++) {              // l = L0 + k
        float d1[5], d2[5];
#pragma unroll
        for (int c5 = 0; c5 < 5; c5++) {
            d1[c5] = w1[c5][0]*x[c5][k+2] + w1[c5][1]*x[c5][k+3] + w1[c5][2]*x[c5][k+4]
                   + w1[c5][3]*x[c5][k+5] + w1[c5][4]*x[c5][k+6];
            d2[c5] = w2[c5][0]*x[c5][k+3] + w2[c5][1]*x[c5][k+4] + w2[c5][2]*x[c5][k+5];
        }
#pragma unroll
        for (int j = 0; j < 5; j++) { acc[j] += d1[j]; acc[20+j] += d2[j]; }
#pragma unroll
        for (int j = 0; j < 5; j++)
#pragma unroll
            for (int kk = j; kk < 5; kk++) {
                int idx = j*(11-j)/2 + (kk - j);
                acc[5+idx]  += d1[j]*d1[kk];
                acc[25+idx] += d2[j]*d2[kk];
            }
    }

    int lane = tid & 63, wv = tid >> 6;
#pragma unroll
    for (int k = 0; k < 40; k++) acc[k] = wave_sum(acc[k]);
    if (lane == 63) {
#pragma unroll
        for (int k = 0; k < 40; k++) red[wv][k] = acc[k];
    }
    __syncthreads();
    if (tid < 40) {
        ws[WS_PART + blockIdx.x * 40 + tid] =
            red[0][tid] + red[1][tid] + red[2][tid] + red[3][tid];
    }

    // F[nn] + bf16 hi/lo prepack; blocks 0..9 own one flw half-row each
    if (blockIdx.x < 10) {
        int nn = blockIdx.x;
        int n = nn < 5 ? nn : nn - 5;
        int off = nn < 5 ? 0 : LL;
        float4 v = *(const float4*)(flw + n * (2*LL) + off + tid * 4);
        {
            unsigned int hp0, lp0, hp1, lp1;
            trunc_pair(v.x, v.y, hp0, lp0);
            trunc_pair(v.z, v.w, hp1, lp1);
            char* fwb = (char*)(ws + WS_FLW);
            *(uint2*)(fwb + nn * 2048 + tid * 8)         = make_uint2(hp0, hp1);
            *(uint2*)(fwb + 32768 + nn * 2048 + tid * 8) = make_uint2(lp0, lp1);
        }
        float s = wave_sum(v.x + v.y + v.z + v.w);
        if (lane == 63) fred[wv] = s;
        __syncthreads();
        if (tid == 0) ws[WS_F + nn] = fred[0] + fred[1] + fred[2] + fred[3];
    } else if (blockIdx.x < 16) {
        int nn = blockIdx.x;
        char* fwb = (char*)(ws + WS_FLW);
        *(uint2*)(fwb + nn * 2048 + tid * 8)         = make_uint2(0u, 0u);
        *(uint2*)(fwb + 32768 + nn * 2048 + tid * 8) = make_uint2(0u, 0u);
    }
}

// ---------------- Kernel 2: reduce partials + BN finalize -> packed consts in GLOBAL ws ----------------
// (r9-verbatim)
__global__ __launch_bounds__(320) void k_prep(
    float* __restrict__ ws,
    const float* __restrict__ pw1, const float* __restrict__ pw2,
    const float* __restrict__ g1,  const float* __restrict__ be1,
    const float* __restrict__ g2,  const float* __restrict__ be2,
    const float* __restrict__ r1w, const float* __restrict__ r2w,
    const float* __restrict__ r1b, const float* __restrict__ r2b)
{
    __shared__ float momS[40];
    int tid = threadIdx.x;
    {
        int k = tid >> 3, sub = tid & 7;
        float v = 0.f;
#pragma unroll 8
        for (int t2 = 0; t2 < 32; t2++) v += ws[WS_PART + (sub + (t2 << 3)) * 40 + k];
        v += __shfl_xor(v, 1, 64);
        v += __shfl_xor(v, 2, 64);
        v += __shfl_xor(v, 4, 64);
        if (sub == 0) momS[k] = v;
    }
    __syncthreads();
    if (tid < 64) {
        int brc = tid >> 5, o = tid & 31;
        const float invN = 1.0f / (float)NTOT;
        const float* pw = brc ? pw2 : pw1;
        const float* rw = brc ? r2w : r1w;
        const float* s  = momS + (brc ? 20 : 0);
        const float* M  = momS + (brc ? 25 : 5);
        float pwv[5], rwv[5], md[5];
#pragma unroll
        for (int j = 0; j < 5; j++) { pwv[j] = pw[o*5+j]; rwv[j] = rw[o*5+j]; md[j] = s[j] * invN; }
        float meanY = 0.f;
#pragma unroll
        for (int j = 0; j < 5; j++) meanY += pwv[j] * md[j];
        float ey2 = 0.f;
#pragma unroll
        for (int j = 0; j < 5; j++)
#pragma unroll
            for (int k = 0; k < 5; k++) {
                int lo = j < k ? j : k, hi = j < k ? k : j;
                int idx = lo*(11-lo)/2 + (hi - lo);
                ey2 += pwv[j] * pwv[k] * (M[idx] * invN);
            }
        float varY = ey2 - meanY * meanY;
        if (varY < 0.f) varY = 0.f;
        float gg = brc ? g2[o] : g1[o];
        float bb = brc ? be2[o] : be1[o];
        float rb = brc ? r2b[o] : r1b[o];
        float sc = gg * rsqrtf(varY + EPSV);
        float sh = bb - meanY * sc;
        float* dst = ws + WS_CONST + tid * 16;
        dst[0] = pwv[0]*sc; dst[1] = pwv[1]*sc; dst[2] = pwv[2]*sc; dst[3] = pwv[3]*sc;
        dst[4] = pwv[4]*sc; dst[5] = sh;        dst[6] = rb;        dst[7] = 0.f;
        dst[8] = rwv[0];    dst[9] = rwv[1];    dst[10] = rwv[2];   dst[11] = rwv[3];
        dst[12] = rwv[4];   dst[13] = 0.f;      dst[14] = 0.f;      dst[15] = 0.f;
    }
}

// ---------------- Kernel 3: r9 barrier-free K-loop, unroll 4 (r15's unroll-2 won ~2us; deeper ILP) ----------------
// r15 post-mortem: unroll 1->2 = first positive K-loop delta in 6 rounds (130.1 -> 128.4 total),
// confirming the per-wave dependency chain is the limiter and ILP is the lever. VGPR headroom
// remains (64 @ unroll1 vs 128 cap). Single change vs r15: unroll 2 -> 4. Failure signature:
// spill (FETCH_SIZE balloon / total >= 132) -> unroll-2 version is final.
__global__ __launch_bounds__(512, 2) void k_fused(
    const float* __restrict__ src,
    const float* __restrict__ dw1,
    const float* __restrict__ dw2,
    const float* __restrict__ ll1w,
    const float* __restrict__ ll1b,
    const float* __restrict__ flb,
    const float* __restrict__ ws_ro,
    float* __restrict__ out)
{
    // base: entry ((br<<11)+(l<<1)+slot) float4s (64KB), byte XOR ((l>>3)&3)<<4
    //   slot0 = (d0,d1,d2,d3), slot1 = (d4, sv0, sv1, sv2)
    // cbase @ float 16384: l -> float2 (sv3, sv4) (8KB)
    // epilogue alias: part = floats [0,4096) (16 tile-slots x 256), Sarr = floats [4096,5120)
    __shared__ __align__(16) float dvS[18432];
    __shared__ float llT[832];   // ll1w transposed: [c*13 + a]
    __shared__ float PQ[130];

    int tid = threadIdx.x, b = blockIdx.x;
    int lane = tid & 63;
    int gu = __builtin_amdgcn_readfirstlane(tid >> 6);  // wave 0..7 (uniform)
    int mp = gu >> 2;                                   // Mtile pair {2mp, 2mp+1}; == branch
    int lq = gu & 3;                                    // l-quarter (Ksteps lq*8 .. lq*8+7)
    int row = lane & 15;                                // ch row within tile == B column nn
    int ko = lane >> 4;                                 // k-octet within Kstep

    const float* srcB = src + b * (5 * LL);
    char* base  = (char*)dvS;
    char* cbase = (char*)(dvS + 16384);

    // ---- one-shot staging (r6/r9-proven): thread t computes d1[5], d2[5], sv[5] for l = t, t+512 ----
    for (int t = tid; t < 1024; t += 512) {
        int swz = ((t >> 3) & 3) << 4;
        float d1v[5], d2v[5], s0[5];
#pragma unroll
        for (int c5 = 0; c5 < 5; c5++) {
            const float* s5 = srcB + (c5 << 10);
            float xm2 = (t >= 2)    ? s5[t - 2] : 0.f;
            float xm1 = (t >= 1)    ? s5[t - 1] : 0.f;
            float x0  = s5[t];
            float xp1 = (t <= 1022) ? s5[t + 1] : 0.f;
            float xp2 = (t <= 1021) ? s5[t + 2] : 0.f;
            d1v[c5] = dw1[c5*5+0]*xm2 + dw1[c5*5+1]*xm1 + dw1[c5*5+2]*x0
                    + dw1[c5*5+3]*xp1 + dw1[c5*5+4]*xp2;
            d2v[c5] = dw2[c5*3+0]*xm1 + dw2[c5*3+1]*x0 + dw2[c5*3+2]*xp1;
            s0[c5] = x0;
        }
        *(float4*)(base + ((((0<<11)+(t<<1)+0) << 4) ^ swz)) = make_float4(d1v[0],d1v[1],d1v[2],d1v[3]);
        *(float4*)(base + ((((0<<11)+(t<<1)+1) << 4) ^ swz)) = make_float4(d1v[4],s0[0],s0[1],s0[2]);
        *(float4*)(base + ((((1<<11)+(t<<1)+0) << 4) ^ swz)) = make_float4(d2v[0],d2v[1],d2v[2],d2v[3]);
        *(float4*)(base + ((((1<<11)+(t<<1)+1) << 4) ^ swz)) = make_float4(d2v[4],s0[0],s0[1],s0[2]);
        *(float2*)(cbase + (t << 3)) = make_float2(s0[3], s0[4]);
    }
    // ---- stage ll1w transposed (epilogue-only; epilogue barriers cover it) ----
    for (int idx = tid; idx < 832; idx += 512) {
        int cc = idx / 13, a = idx - cc * 13;
        llT[idx] = ll1w[a * 64 + cc];
    }
    __syncthreads();

    // ---- per-lane consts for the 2 channels (13 regs each) ----
    int chA = (mp << 5) + row;           // tile 2mp
    int chB = chA + 16;                  // tile 2mp+1
    const float* cfA = ws_ro + WS_CONST + (chA << 4);
    const float4 Aa = *(const float4*)cfA;
    const float4 Ba = *(const float4*)(cfA + 4);
    const float4 Ra = *(const float4*)(cfA + 8);
    const float  a4 = cfA[12];
    const float* cfB = ws_ro + WS_CONST + (chB << 4);
    const float4 Ab = *(const float4*)cfB;
    const float4 Bb = *(const float4*)(cfB + 4);
    const float4 Rb = *(const float4*)(cfB + 8);
    const float  b4 = cfB[12];

    const char* fwb = (const char*)(ws_ro + WS_FLW);
    floatx4 CA = {0.f, 0.f, 0.f, 0.f};
    floatx4 CB = {0.f, 0.f, 0.f, 0.f};

#pragma unroll 4
    for (int s = 0; s < 8; ++s) {
        int kstep = (lq << 3) + s;
        int l0 = (kstep << 5) + (ko << 3);       // lane's octet base (global l)
        // B frags for this Kstep (prepacked; latency hides under e-compute)
        union { uint4 u; bhalf8 v; } bh, bl;
        {
            int boff = ((row << 10) + l0) << 1;
            bh.u = *(const uint4*)(fwb + boff);
            bl.u = *(const uint4*)(fwb + 32768 + boff);
        }
        // e for 8 l x 2 ch; dv read ONCE per l (serves both channels)
        int sw = ((l0 >> 3) & 3) << 4;
        int ebase = (mp << 15) + (l0 << 5);      // byte base of this octet's entries (br = mp)
        union { unsigned int u[4]; bhalf8 v; } ahA, alA, ahB, alB;
#pragma unroll
        for (int jp = 0; jp < 4; ++jp) {
            int o0 = ebase + (jp << 6);          // two l's = 4 slots = 64B
            const float4 pa0 = *(const float4*)(base + ((o0      ) ^ sw));
            const float4 pb0 = *(const float4*)(base + ((o0 + 16) ^ sw));
            const float4 pa1 = *(const float4*)(base + ((o0 + 32) ^ sw));
            const float4 pb1 = *(const float4*)(base + ((o0 + 48) ^ sw));
            const float4 pcc = *(const float4*)(cbase + ((l0 + (jp << 1)) << 3));  // (sv3,sv4) x2
            float e0 = e_val(Aa, Ba, Ra, a4, pa0, pb0, pcc.x, pcc.y);
            float e1 = e_val(Aa, Ba, Ra, a4, pa1, pb1, pcc.z, pcc.w);
            trunc_pair(e0, e1, ahA.u[jp], alA.u[jp]);
            float f0 = e_val(Ab, Bb, Rb, b4, pa0, pb0, pcc.x, pcc.y);
            float f1 = e_val(Ab, Bb, Rb, b4, pa1, pb1, pcc.z, pcc.w);
            trunc_pair(f0, f1, ahB.u[jp], alB.u[jp]);
        }
        CA = __builtin_amdgcn_mfma_f32_16x16x32_bf16(ahA.v, bh.v, CA, 0, 0, 0);
        CA = __builtin_amdgcn_mfma_f32_16x16x32_bf16(ahA.v, bl.v, CA, 0, 0, 0);
        CA = __builtin_amdgcn_mfma_f32_16x16x32_bf16(alA.v, bh.v, CA, 0, 0, 0);
        CB = __builtin_amdgcn_mfma_f32_16x16x32_bf16(ahB.v, bh.v, CB, 0, 0, 0);
        CB = __builtin_amdgcn_mfma_f32_16x16x32_bf16(ahB.v, bl.v, CB, 0, 0, 0);
        CB = __builtin_amdgcn_mfma_f32_16x16x32_bf16(alB.v, bh.v, CB, 0, 0, 0);
    }

    // ---- cross-wave reduce: 16 tile-slots (gu x {A,B}) of 256 floats each ----
    __syncthreads();   // all dvS reads done; alias as part scratch
    {
        float* part = dvS;
        // C layout: col = lane&15 (nn), row = (lane>>4)*4 + reg -> tile offset = row*16+col
        int basep = ((lane >> 4) << 6) + (lane & 15);
        int sA = (gu << 1) * 256, sB = sA + 256;
        part[sA + basep]      = CA[0];
        part[sA + basep + 16] = CA[1];
        part[sA + basep + 32] = CA[2];
        part[sA + basep + 48] = CA[3];
        part[sB + basep]      = CB[0];
        part[sB + basep + 16] = CB[1];
        part[sB + basep + 32] = CB[2];
        part[sB + basep + 48] = CB[3];
    }
    __syncthreads();
    float* SarrF = dvS + 4096;     // S[c][n], 64 x 16 (after the 4096-float part region)
    for (int idx = tid; idx < 1024; idx += 512) {
        int c = idx >> 4, n = idx & 15;
        int mt2 = c >> 4, m = c & 15;
        int mp2 = mt2 >> 1, t2 = mt2 & 1;
        const float* part = (const float*)dvS;
        int o = (m << 4) + n;
        float sum = 0.f;
#pragma unroll
        for (int lq2 = 0; lq2 < 4; ++lq2)
            sum += part[((((mp2 << 2) + lq2) << 1) + t2) * 256 + o];
        SarrF[idx] = sum;
    }
    __syncthreads();

    // ---- PQ[half][a][n] = sum_c llT[c][a] * S[c][half*5+n] + ll1b[a] * F[half*5+n] ----
    if (tid < 130) {
        int half = tid >= 65 ? 1 : 0;
        int q = tid - half * 65;
        int a = q / 5, n = q - a * 5;
        int col = half * 5 + n;
        float v = ll1b[a] * ws_ro[WS_F + col];
#pragma unroll 8
        for (int cc = 0; cc < 64; cc++) v += llT[cc * 13 + a] * SarrF[(cc << 4) + col];
        PQ[tid] = v;
    }
    __syncthreads();

    // ---- out[b,i,j,n] = P[min,n] + Q[max,n] + flb[n] ----
    for (int idx = tid; idx < AA * AA * NBP; idx += 512) {
        int i = idx / 65;
        int rr = idx - i * 65;
        int j = rr / 5, n = rr - j * 5;
        int mn = i < j ? i : j, mx = i < j ? j : i;
        out[b * (AA * AA * NBP) + idx] = PQ[mn * 5 + n] + PQ[65 + mx * 5 + n] + flb[n];
    }
}

extern "C" void kernel_launch(void* const* d_in, const int* in_sizes, int n_in,
                              void* d_out, int out_size, void* d_ws, size_t ws_size,
                              hipStream_t stream) {
    const float* src  = (const float*)d_in[0];
    // d_in[1] = mask (unused), d_in[2] = max_atoms (unused, == 13)
    const float* dw1  = (const float*)d_in[3];
    const float* pw1  = (const float*)d_in[4];
    const float* g1   = (const float*)d_in[5];
    const float* be1  = (const float*)d_in[6];
    const float* r1w  = (const float*)d_in[7];
    const float* r1b  = (const float*)d_in[8];
    const float* dw2  = (const float*)d_in[9];
    const float* pw2  = (const float*)d_in[10];
    const float* g2   = (const float*)d_in[11];
    const float* be2  = (const float*)d_in[12];
    const float* r2w  = (const float*)d_in[13];
    const float* r2b  = (const float*)d_in[14];
    const float* ll1w = (const float*)d_in[15];
    const float* ll1b = (const float*)d_in[16];
    const float* flw  = (const float*)d_in[17];
    const float* flb  = (const float*)d_in[18];
    float* ws  = (float*)d_ws;
    float* out = (float*)d_out;

    k_moments<<<256, 256, 0, stream>>>(src, dw1, dw2, flw, ws);
    k_prep<<<1, 320, 0, stream>>>(ws, pw1, pw2, g1, be1, g2, be2, r1w, r2w, r1b, r2b);
    k_fused<<<BB, 512, 0, stream>>>(src, dw1, dw2, ll1w, ll1b, flb, ws, out);
}

// Round 17
// 127.489 us; speedup vs baseline: 1.0449x; 1.0449x over previous
//
#include <hip/hip_runtime.h>
#include <hip/hip_bf16.h>

// Problem constants
#define BB 512
#define LL 1024
#define AA 13
#define NBP 5
#define NTOT (BB * LL)
#define EPSV 1e-5f

// ws layout (floats)
#define WS_F     192       // 10: F[nn] = sum over half-l of flw
#define WS_PART  256       // 256 blocks * 40 moment partials
#define WS_CONST 10496     // 64 channels * 16 packed consts (written by k_prep)
#define WS_FLW   16384     // 64KB region: flw bf16 hi plane [0,32K)B, lo plane [32K,64K)B, 16 rows x 1024

typedef __attribute__((ext_vector_type(8))) short bhalf8;   // 8 bf16 in 4 VGPRs (MFMA A/B frag)
typedef __attribute__((ext_vector_type(4))) float floatx4;  // MFMA C/D frag

// ---- truncation hi/lo split, packed 2-at-a-time (r1/r2/r6/r9/r15-proven numerics: absmax 0.0039) ----
__device__ __forceinline__ void trunc_pair(float e0, float e1, unsigned int& hp, unsigned int& lp) {
    unsigned int u0 = __float_as_uint(e0), u1 = __float_as_uint(e1);
    unsigned int h0 = u0 & 0xFFFF0000u, h1 = u1 & 0xFFFF0000u;
    hp = (h0 >> 16) | h1;
    float l0 = e0 - __uint_as_float(h0);
    float l1 = e1 - __uint_as_float(h1);
    lp = (__float_as_uint(l0) >> 16) | (__float_as_uint(l1) & 0xFFFF0000u);
}

// ---- DPP wave64 sum: result valid in lane 63 (VALU pipe, no LDS) ----
template<int CTRL, int RM, bool BC>
__device__ __forceinline__ float dppadd(float v) {
    int t = __builtin_amdgcn_update_dpp(0, __float_as_int(v), CTRL, RM, 0xf, BC);
    return v + __int_as_float(t);
}
__device__ __forceinline__ float wave_sum(float v) {
    v = dppadd<0x111, 0xf, true >(v);   // row_shr:1
    v = dppadd<0x112, 0xf, true >(v);   // row_shr:2
    v = dppadd<0x114, 0xf, true >(v);   // row_shr:4
    v = dppadd<0x118, 0xf, true >(v);   // row_shr:8
    v = dppadd<0x142, 0xa, false>(v);   // row_bcast15
    v = dppadd<0x143, 0xc, false>(v);   // row_bcast31 -> lane63 total
    return v;
}

// ---- e from packed dv slots + per-channel consts ----
__device__ __forceinline__ float e_val(const float4& A, const float4& B2, const float4& R0, float r4w,
                                       const float4& pa, const float4& pb, float svx, float svy) {
    float y = B2.y + A.x*pa.x + A.y*pa.y + A.z*pa.z + A.w*pa.w + B2.x*pb.x;
    float r = B2.z + R0.x*pb.y + R0.y*pb.z + R0.z*pb.w + R0.w*svx + r4w*svy;
    return fmaxf(y, 0.f) * r;
}

// ---------------- Kernel 1: moment partials + flw half-row sums + flw bf16 hi/lo prepack ----------------
// (r9-verbatim, proven: 256 blocks x 256 thr, 8-wide strips)
__global__ __launch_bounds__(256) void k_moments(
    const float* __restrict__ src,
    const float* __restrict__ dw1,
    const float* __restrict__ dw2,
    const float* __restrict__ flw,
    float* __restrict__ ws)
{
    __shared__ float red[4][40];
    __shared__ float fred[4];
    int tid = threadIdx.x;
    int gid = blockIdx.x * 256 + tid;
    int b = gid >> 7, L0 = (gid & 127) << 3;     // 8-wide strip per thread
    const float* sb = src + b * (5 * LL);

    float w1[5][5], w2[5][3];
#pragma unroll
    for (int c = 0; c < 5; c++) {
#pragma unroll
        for (int t = 0; t < 5; t++) w1[c][t] = dw1[c*5+t];
#pragma unroll
        for (int t = 0; t < 3; t++) w2[c][t] = dw2[c*3+t];
    }

    // x[c5][m] covers l = L0-4 .. L0+11
    float x[5][16];
#pragma unroll
    for (int c5 = 0; c5 < 5; c5++) {
        const float* sp = sb + c5 * LL;
        float4 xa = (L0 >= 4)    ? *(const float4*)(sp + L0 - 4) : make_float4(0,0,0,0);
        float4 xb = *(const float4*)(sp + L0);
        float4 xc = *(const float4*)(sp + L0 + 4);
        float4 xd = (L0 <= 1012) ? *(const float4*)(sp + L0 + 8) : make_float4(0,0,0,0);
        x[c5][0]=xa.x; x[c5][1]=xa.y; x[c5][2]=xa.z; x[c5][3]=xa.w;
        x[c5][4]=xb.x; x[c5][5]=xb.y; x[c5][6]=xb.z; x[c5][7]=xb.w;
        x[c5][8]=xc.x; x[c5][9]=xc.y; x[c5][10]=xc.z; x[c5][11]=xc.w;
        x[c5][12]=xd.x; x[c5][13]=xd.y; x[c5][14]=xd.z; x[c5][15]=xd.w;
    }

    float acc[40];
#pragma unroll
    for (int k = 0; k < 40; k++) acc[k] = 0.f;

#pragma unroll
    for (int k = 0; k < 8; k++) {              // l = L0 + k
        float d1[5], d2[5];
#pragma unroll
        for (int c5 = 0; c5 < 5; c5++) {
            d1[c5] = w1[c5][0]*x[c5][k+2] + w1[c5][1]*x[c5][k+3] + w1[c5][2]*x[c5][k+4]
                   + w1[c5][3]*x[c5][k+5] + w1[c5][4]*x[c5][k+6];
            d2[c5] = w2[c5][0]*x[c5][k+3] + w2[c5][1]*x[c5][k+4] + w2[c5][2]*x[c5][k+5];
        }
#pragma unroll
        for (int j = 0; j < 5; j++) { acc[j] += d1[j]; acc[20+j] += d2[j]; }
#pragma unroll
        for (int j = 0; j < 5; j++)
#pragma unroll
            for (int kk = j; kk < 5; kk++) {
                int idx = j*(11-j)/2 + (kk - j);
                acc[5+idx]  += d1[j]*d1[kk];
                acc[25+idx] += d2[j]*d2[kk];
            }
    }

    int lane = tid & 63, wv = tid >> 6;
#pragma unroll
    for (int k = 0; k < 40; k++) acc[k] = wave_sum(acc[k]);
    if (lane == 63) {
#pragma unroll
        for (int k = 0; k < 40; k++) red[wv][k] = acc[k];
    }
    __syncthreads();
    if (tid < 40) {
        ws[WS_PART + blockIdx.x * 40 + tid] =
            red[0][tid] + red[1][tid] + red[2][tid] + red[3][tid];
    }

    // F[nn] + bf16 hi/lo prepack; blocks 0..9 own one flw half-row each
    if (blockIdx.x < 10) {
        int nn = blockIdx.x;
        int n = nn < 5 ? nn : nn - 5;
        int off = nn < 5 ? 0 : LL;
        float4 v = *(const float4*)(flw + n * (2*LL) + off + tid * 4);
        {
            unsigned int hp0, lp0, hp1, lp1;
            trunc_pair(v.x, v.y, hp0, lp0);
            trunc_pair(v.z, v.w, hp1, lp1);
            char* fwb = (char*)(ws + WS_FLW);
            *(uint2*)(fwb + nn * 2048 + tid * 8)         = make_uint2(hp0, hp1);
            *(uint2*)(fwb + 32768 + nn * 2048 + tid * 8) = make_uint2(lp0, lp1);
        }
        float s = wave_sum(v.x + v.y + v.z + v.w);
        if (lane == 63) fred[wv] = s;
        __syncthreads();
        if (tid == 0) ws[WS_F + nn] = fred[0] + fred[1] + fred[2] + fred[3];
    } else if (blockIdx.x < 16) {
        int nn = blockIdx.x;
        char* fwb = (char*)(ws + WS_FLW);
        *(uint2*)(fwb + nn * 2048 + tid * 8)         = make_uint2(0u, 0u);
        *(uint2*)(fwb + 32768 + nn * 2048 + tid * 8) = make_uint2(0u, 0u);
    }
}

// ---------------- Kernel 2: reduce partials + BN finalize -> packed consts in GLOBAL ws ----------------
// (r9-verbatim)
__global__ __launch_bounds__(320) void k_prep(
    float* __restrict__ ws,
    const float* __restrict__ pw1, const float* __restrict__ pw2,
    const float* __restrict__ g1,  const float* __restrict__ be1,
    const float* __restrict__ g2,  const float* __restrict__ be2,
    const float* __restrict__ r1w, const float* __restrict__ r2w,
    const float* __restrict__ r1b, const float* __restrict__ r2b)
{
    __shared__ float momS[40];
    int tid = threadIdx.x;
    {
        int k = tid >> 3, sub = tid & 7;
        float v = 0.f;
#pragma unroll 8
        for (int t2 = 0; t2 < 32; t2++) v += ws[WS_PART + (sub + (t2 << 3)) * 40 + k];
        v += __shfl_xor(v, 1, 64);
        v += __shfl_xor(v, 2, 64);
        v += __shfl_xor(v, 4, 64);
        if (sub == 0) momS[k] = v;
    }
    __syncthreads();
    if (tid < 64) {
        int brc = tid >> 5, o = tid & 31;
        const float invN = 1.0f / (float)NTOT;
        const float* pw = brc ? pw2 : pw1;
        const float* rw = brc ? r2w : r1w;
        const float* s  = momS + (brc ? 20 : 0);
        const float* M  = momS + (brc ? 25 : 5);
        float pwv[5], rwv[5], md[5];
#pragma unroll
        for (int j = 0; j < 5; j++) { pwv[j] = pw[o*5+j]; rwv[j] = rw[o*5+j]; md[j] = s[j] * invN; }
        float meanY = 0.f;
#pragma unroll
        for (int j = 0; j < 5; j++) meanY += pwv[j] * md[j];
        float ey2 = 0.f;
#pragma unroll
        for (int j = 0; j < 5; j++)
#pragma unroll
            for (int k = 0; k < 5; k++) {
                int lo = j < k ? j : k, hi = j < k ? k : j;
                int idx = lo*(11-lo)/2 + (hi - lo);
                ey2 += pwv[j] * pwv[k] * (M[idx] * invN);
            }
        float varY = ey2 - meanY * meanY;
        if (varY < 0.f) varY = 0.f;
        float gg = brc ? g2[o] : g1[o];
        float bb = brc ? be2[o] : be1[o];
        float rb = brc ? r2b[o] : r1b[o];
        float sc = gg * rsqrtf(varY + EPSV);
        float sh = bb - meanY * sc;
        float* dst = ws + WS_CONST + tid * 16;
        dst[0] = pwv[0]*sc; dst[1] = pwv[1]*sc; dst[2] = pwv[2]*sc; dst[3] = pwv[3]*sc;
        dst[4] = pwv[4]*sc; dst[5] = sh;        dst[6] = rb;        dst[7] = 0.f;
        dst[8] = rwv[0];    dst[9] = rwv[1];    dst[10] = rwv[2];   dst[11] = rwv[3];
        dst[12] = rwv[4];   dst[13] = 0.f;      dst[14] = 0.f;      dst[15] = 0.f;
    }
}

// ---------------- Kernel 3: r15-verbatim (best measured: 128.4us total) ----------------
// r16 post-mortem: unroll 4 regressed (133.2) — transients exceed the 128-VGPR cap, the predicted
// spill signature. unroll 2 is the proven sweet spot on the ds_read->FMA->pack->MFMA chain:
// 2 iterations' loads interleave under FMAs within register budget. Locked final.
__global__ __launch_bounds__(512, 2) void k_fused(
    const float* __restrict__ src,
    const float* __restrict__ dw1,
    const float* __restrict__ dw2,
    const float* __restrict__ ll1w,
    const float* __restrict__ ll1b,
    const float* __restrict__ flb,
    const float* __restrict__ ws_ro,
    float* __restrict__ out)
{
    // base: entry ((br<<11)+(l<<1)+slot) float4s (64KB), byte XOR ((l>>3)&3)<<4
    //   slot0 = (d0,d1,d2,d3), slot1 = (d4, sv0, sv1, sv2)
    // cbase @ float 16384: l -> float2 (sv3, sv4) (8KB)
    // epilogue alias: part = floats [0,4096) (16 tile-slots x 256), Sarr = floats [4096,5120)
    __shared__ __align__(16) float dvS[18432];
    __shared__ float llT[832];   // ll1w transposed: [c*13 + a]
    __shared__ float PQ[130];

    int tid = threadIdx.x, b = blockIdx.x;
    int lane = tid & 63;
    int gu = __builtin_amdgcn_readfirstlane(tid >> 6);  // wave 0..7 (uniform)
    int mp = gu >> 2;                                   // Mtile pair {2mp, 2mp+1}; == branch
    int lq = gu & 3;                                    // l-quarter (Ksteps lq*8 .. lq*8+7)
    int row = lane & 15;                                // ch row within tile == B column nn
    int ko = lane >> 4;                                 // k-octet within Kstep

    const float* srcB = src + b * (5 * LL);
    char* base  = (char*)dvS;
    char* cbase = (char*)(dvS + 16384);

    // ---- one-shot staging (r6/r9-proven): thread t computes d1[5], d2[5], sv[5] for l = t, t+512 ----
    for (int t = tid; t < 1024; t += 512) {
        int swz = ((t >> 3) & 3) << 4;
        float d1v[5], d2v[5], s0[5];
#pragma unroll
        for (int c5 = 0; c5 < 5; c5++) {
            const float* s5 = srcB + (c5 << 10);
            float xm2 = (t >= 2)    ? s5[t - 2] : 0.f;
            float xm1 = (t >= 1)    ? s5[t - 1] : 0.f;
            float x0  = s5[t];
            float xp1 = (t <= 1022) ? s5[t + 1] : 0.f;
            float xp2 = (t <= 1021) ? s5[t + 2] : 0.f;
            d1v[c5] = dw1[c5*5+0]*xm2 + dw1[c5*5+1]*xm1 + dw1[c5*5+2]*x0
                    + dw1[c5*5+3]*xp1 + dw1[c5*5+4]*xp2;
            d2v[c5] = dw2[c5*3+0]*xm1 + dw2[c5*3+1]*x0 + dw2[c5*3+2]*xp1;
            s0[c5] = x0;
        }
        *(float4*)(base + ((((0<<11)+(t<<1)+0) << 4) ^ swz)) = make_float4(d1v[0],d1v[1],d1v[2],d1v[3]);
        *(float4*)(base + ((((0<<11)+(t<<1)+1) << 4) ^ swz)) = make_float4(d1v[4],s0[0],s0[1],s0[2]);
        *(float4*)(base + ((((1<<11)+(t<<1)+0) << 4) ^ swz)) = make_float4(d2v[0],d2v[1],d2v[2],d2v[3]);
        *(float4*)(base + ((((1<<11)+(t<<1)+1) << 4) ^ swz)) = make_float4(d2v[4],s0[0],s0[1],s0[2]);
        *(float2*)(cbase + (t << 3)) = make_float2(s0[3], s0[4]);
    }
    // ---- stage ll1w transposed (epilogue-only; epilogue barriers cover it) ----
    for (int idx = tid; idx < 832; idx += 512) {
        int cc = idx / 13, a = idx - cc * 13;
        llT[idx] = ll1w[a * 64 + cc];
    }
    __syncthreads();

    // ---- per-lane consts for the 2 channels (13 regs each) ----
    int chA = (mp << 5) + row;           // tile 2mp
    int chB = chA + 16;                  // tile 2mp+1
    const float* cfA = ws_ro + WS_CONST + (chA << 4);
    const float4 Aa = *(const float4*)cfA;
    const float4 Ba = *(const float4*)(cfA + 4);
    const float4 Ra = *(const float4*)(cfA + 8);
    const float  a4 = cfA[12];
    const float* cfB = ws_ro + WS_CONST + (chB << 4);
    const float4 Ab = *(const float4*)cfB;
    const float4 Bb = *(const float4*)(cfB + 4);
    const float4 Rb = *(const float4*)(cfB + 8);
    const float  b4 = cfB[12];

    const char* fwb = (const char*)(ws_ro + WS_FLW);
    floatx4 CA = {0.f, 0.f, 0.f, 0.f};
    floatx4 CB = {0.f, 0.f, 0.f, 0.f};

#pragma unroll 2
    for (int s = 0; s < 8; ++s) {
        int kstep = (lq << 3) + s;
        int l0 = (kstep << 5) + (ko << 3);       // lane's octet base (global l)
        // B frags for this Kstep (prepacked; latency hides under e-compute)
        union { uint4 u; bhalf8 v; } bh, bl;
        {
            int boff = ((row << 10) + l0) << 1;
            bh.u = *(const uint4*)(fwb + boff);
            bl.u = *(const uint4*)(fwb + 32768 + boff);
        }
        // e for 8 l x 2 ch; dv read ONCE per l (serves both channels)
        int sw = ((l0 >> 3) & 3) << 4;
        int ebase = (mp << 15) + (l0 << 5);      // byte base of this octet's entries (br = mp)
        union { unsigned int u[4]; bhalf8 v; } ahA, alA, ahB, alB;
#pragma unroll
        for (int jp = 0; jp < 4; ++jp) {
            int o0 = ebase + (jp << 6);          // two l's = 4 slots = 64B
            const float4 pa0 = *(const float4*)(base + ((o0      ) ^ sw));
            const float4 pb0 = *(const float4*)(base + ((o0 + 16) ^ sw));
            const float4 pa1 = *(const float4*)(base + ((o0 + 32) ^ sw));
            const float4 pb1 = *(const float4*)(base + ((o0 + 48) ^ sw));
            const float4 pcc = *(const float4*)(cbase + ((l0 + (jp << 1)) << 3));  // (sv3,sv4) x2
            float e0 = e_val(Aa, Ba, Ra, a4, pa0, pb0, pcc.x, pcc.y);
            float e1 = e_val(Aa, Ba, Ra, a4, pa1, pb1, pcc.z, pcc.w);
            trunc_pair(e0, e1, ahA.u[jp], alA.u[jp]);
            float f0 = e_val(Ab, Bb, Rb, b4, pa0, pb0, pcc.x, pcc.y);
            float f1 = e_val(Ab, Bb, Rb, b4, pa1, pb1, pcc.z, pcc.w);
            trunc_pair(f0, f1, ahB.u[jp], alB.u[jp]);
        }
        CA = __builtin_amdgcn_mfma_f32_16x16x32_bf16(ahA.v, bh.v, CA, 0, 0, 0);
        CA = __builtin_amdgcn_mfma_f32_16x16x32_bf16(ahA.v, bl.v, CA, 0, 0, 0);
        CA = __builtin_amdgcn_mfma_f32_16x16x32_bf16(alA.v, bh.v, CA, 0, 0, 0);
        CB = __builtin_amdgcn_mfma_f32_16x16x32_bf16(ahB.v, bh.v, CB, 0, 0, 0);
        CB = __builtin_amdgcn_mfma_f32_16x16x32_bf16(ahB.v, bl.v, CB, 0, 0, 0);
        CB = __builtin_amdgcn_mfma_f32_16x16x32_bf16(alB.v, bh.v, CB, 0, 0, 0);
    }

    // ---- cross-wave reduce: 16 tile-slots (gu x {A,B}) of 256 floats each ----
    __syncthreads();   // all dvS reads done; alias as part scratch
    {
        float* part = dvS;
        // C layout: col = lane&15 (nn), row = (lane>>4)*4 + reg -> tile offset = row*16+col
        int basep = ((lane >> 4) << 6) + (lane & 15);
        int sA = (gu << 1) * 256, sB = sA + 256;
        part[sA + basep]      = CA[0];
        part[sA + basep + 16] = CA[1];
        part[sA + basep + 32] = CA[2];
        part[sA + basep + 48] = CA[3];
        part[sB + basep]      = CB[0];
        part[sB + basep + 16] = CB[1];
        part[sB + basep + 32] = CB[2];
        part[sB + basep + 48] = CB[3];
    }
    __syncthreads();
    float* SarrF = dvS + 4096;     // S[c][n], 64 x 16 (after the 4096-float part region)
    for (int idx = tid; idx < 1024; idx += 512) {
        int c = idx >> 4, n = idx & 15;
        int mt2 = c >> 4, m = c & 15;
        int mp2 = mt2 >> 1, t2 = mt2 & 1;
        const float* part = (const float*)dvS;
        int o = (m << 4) + n;
        float sum = 0.f;
#pragma unroll
        for (int lq2 = 0; lq2 < 4; ++lq2)
            sum += part[((((mp2 << 2) + lq2) << 1) + t2) * 256 + o];
        SarrF[idx] = sum;
    }
    __syncthreads();

    // ---- PQ[half][a][n] = sum_c llT[c][a] * S[c][half*5+n] + ll1b[a] * F[half*5+n] ----
    if (tid < 130) {
        int half = tid >= 65 ? 1 : 0;
        int q = tid - half * 65;
        int a = q / 5, n = q - a * 5;
        int col = half * 5 + n;
        float v = ll1b[a] * ws_ro[WS_F + col];
#pragma unroll 8
        for (int cc = 0; cc < 64; cc++) v += llT[cc * 13 + a] * SarrF[(cc << 4) + col];
        PQ[tid] = v;
    }
    __syncthreads();

    // ---- out[b,i,j,n] = P[min,n] + Q[max,n] + flb[n] ----
    for (int idx = tid; idx < AA * AA * NBP; idx += 512) {
        int i = idx / 65;
        int rr = idx - i * 65;
        int j = rr / 5, n = rr - j * 5;
        int mn = i < j ? i : j, mx = i < j ? j : i;
        out[b * (AA * AA * NBP) + idx] = PQ[mn * 5 + n] + PQ[65 + mx * 5 + n] + flb[n];
    }
}

extern "C" void kernel_launch(void* const* d_in, const int* in_sizes, int n_in,
                              void* d_out, int out_size, void* d_ws, size_t ws_size,
                              hipStream_t stream) {
    const float* src  = (const float*)d_in[0];
    // d_in[1] = mask (unused), d_in[2] = max_atoms (unused, == 13)
    const float* dw1  = (const float*)d_in[3];
    const float* pw1  = (const float*)d_in[4];
    const float* g1   = (const float*)d_in[5];
    const float* be1  = (const float*)d_in[6];
    const float* r1w  = (const float*)d_in[7];
    const float* r1b  = (const float*)d_in[8];
    const float* dw2  = (const float*)d_in[9];
    const float* pw2  = (const float*)d_in[10];
    const float* g2   = (const float*)d_in[11];
    const float* be2  = (const float*)d_in[12];
    const float* r2w  = (const float*)d_in[13];
    const float* r2b  = (const float*)d_in[14];
    const float* ll1w = (const float*)d_in[15];
    const float* ll1b = (const float*)d_in[16];
    const float* flw  = (const float*)d_in[17];
    const float* flb  = (const float*)d_in[18];
    float* ws  = (float*)d_ws;
    float* out = (float*)d_out;

    k_moments<<<256, 256, 0, stream>>>(src, dw1, dw2, flw, ws);
    k_prep<<<1, 320, 0, stream>>>(ws, pw1, pw2, g1, be1, g2, be2, r1w, r2w, r1b, r2b);
    k_fused<<<BB, 512, 0, stream>>>(src, dw1, dw2, ll1w, ll1b, flb, ws, out);
}